// Round 2
// baseline (1637.081 us; speedup 1.0000x reference)
//
#include <hip/hip_runtime.h>
#include <hip/hip_bf16.h>

#define HH  64
#define BLK 64
#define EPSL 0.1f

// tanh via hardware exp + precise divide (no fast-math flags assumed).
// Handles saturation: e=inf -> 1, e=0 -> -1. Accuracy ~1e-7 rel.
__device__ __forceinline__ float fast_tanh(float x) {
    float e = __expf(2.0f * x);
    return 1.0f - 2.0f / (e + 1.0f);
}

// Tiny pre-pass: W1T[j][i] = W1[i][j] so phase F can s_load contiguous columns.
__global__ void transpose64(const float* __restrict__ W, float* __restrict__ WT) {
    int i = threadIdx.x;   // 0..63
    int j = blockIdx.x;    // 0..63
    WT[j * HH + i] = W[i * HH + j];
}

extern "C" __global__ void __launch_bounds__(BLK)
lnn_kernel(const float* __restrict__ x,
           const float* __restrict__ W0, const float* __restrict__ b0,
           const float* __restrict__ W1, const float* __restrict__ b1,
           const float* __restrict__ W2, const float* __restrict__ b2,
           const float* __restrict__ W3,
           const float* __restrict__ W1T,
           float* __restrict__ out)
{
    // per-thread LDS slots: h1/th1, later reused as dz1/t_dz1.
    __shared__ float h1s[HH][BLK];
    __shared__ float th1s[HH][BLK];

    const int tid = threadIdx.x;
    const long s = (long)blockIdx.x * BLK + tid;

    const float2 xv = *(const float2*)(x + 2 * s);
    const float x0 = xv.x, x1 = xv.y;

    // ---------------- Phase B: z1/tz1 accumulation (h0 computed on the fly)
    {
        float z1[HH], tz1[HH];
        #pragma unroll
        for (int j = 0; j < HH; ++j) { z1[j] = b1[j]; tz1[j] = 0.0f; }

        #pragma unroll 1
        for (int i = 0; i < HH; ++i) {
            const float w0a = W0[i];          // W0[0][i]
            const float w0b = W0[HH + i];     // W0[1][i]
            const float z0  = fmaf(x0, w0a, fmaf(x1, w0b, b0[i]));
            const float h0  = fast_tanh(z0);
            const float th0 = (1.0f - h0 * h0) * w0b;   // tangent dir e1
            const float* __restrict__ row = W1 + i * HH;
            #pragma unroll
            for (int j = 0; j < HH; ++j) {
                const float w = row[j];
                z1[j]  = fmaf(h0,  w, z1[j]);
                tz1[j] = fmaf(th0, w, tz1[j]);
            }
        }
        // epilogue: h1/th1 -> LDS
        #pragma unroll
        for (int j = 0; j < HH; ++j) {
            const float h1  = fast_tanh(z1[j]);
            const float th1 = (1.0f - h1 * h1) * tz1[j];
            h1s[j][tid]  = h1;
            th1s[j][tid] = th1;
        }
    }

    // ---------------- Phase C: z2/tz2 accumulation, then transform to dz2/t_dz2
    float dz2[HH], tdz2[HH];   // first hold z2/tz2, transformed in place
    {
        #pragma unroll
        for (int j = 0; j < HH; ++j) { dz2[j] = b2[j]; tdz2[j] = 0.0f; }

        #pragma unroll 1
        for (int i = 0; i < HH; ++i) {
            const float h1  = h1s[i][tid];
            const float th1 = th1s[i][tid];
            const float* __restrict__ row = W2 + i * HH;
            #pragma unroll
            for (int j = 0; j < HH; ++j) {
                const float w = row[j];
                dz2[j]  = fmaf(h1,  w, dz2[j]);
                tdz2[j] = fmaf(th1, w, tdz2[j]);
            }
        }
        // D epilogue: dz2 = W3*(1-h2^2), t_dz2 = -2*W3*h2*th2
        #pragma unroll
        for (int j = 0; j < HH; ++j) {
            const float h2  = fast_tanh(dz2[j]);
            const float A   = 1.0f - h2 * h2;
            const float th2 = A * tdz2[j];
            const float w3  = W3[j];
            dz2[j]  = w3 * A;
            tdz2[j] = -2.0f * w3 * h2 * th2;
        }
    }

    // ---------------- Phase E: g1/tg1 per i, transform to dz1/t_dz1 (reuse LDS slots)
    #pragma unroll 1
    for (int i = 0; i < HH; ++i) {
        const float* __restrict__ row = W2 + i * HH;
        float g1 = 0.0f, tg1 = 0.0f;
        #pragma unroll
        for (int j = 0; j < HH; ++j) {
            const float w = row[j];
            g1  = fmaf(w, dz2[j],  g1);
            tg1 = fmaf(w, tdz2[j], tg1);
        }
        const float h1  = h1s[i][tid];
        const float th1 = th1s[i][tid];
        const float A   = 1.0f - h1 * h1;
        const float d1  = g1 * A;
        const float td1 = fmaf(tg1, A, -2.0f * g1 * h1 * th1);
        h1s[i][tid]  = d1;    // dz1
        th1s[i][tid] = td1;   // t_dz1
    }

    // ---------------- Phase F: g0/tg0 accumulation over j (needs W1 columns = W1T rows)
    float grad0 = 0.0f, hvp0 = 0.0f, hvp1 = 0.0f;
    {
        float g0[HH], tg0[HH];
        #pragma unroll
        for (int i = 0; i < HH; ++i) { g0[i] = 0.0f; tg0[i] = 0.0f; }

        #pragma unroll 1
        for (int j = 0; j < HH; ++j) {
            const float d1  = h1s[j][tid];
            const float td1 = th1s[j][tid];
            const float* __restrict__ row = W1T + j * HH;
            #pragma unroll
            for (int i = 0; i < HH; ++i) {
                const float w = row[i];
                g0[i]  = fmaf(w, d1,  g0[i]);
                tg0[i] = fmaf(w, td1, tg0[i]);
            }
        }
        // epilogue: recompute h0, fold into the three scalar dots
        #pragma unroll
        for (int i = 0; i < HH; ++i) {
            const float w0a = W0[i];
            const float w0b = W0[HH + i];
            const float z0  = fmaf(x0, w0a, fmaf(x1, w0b, b0[i]));
            const float h0  = fast_tanh(z0);
            const float A   = 1.0f - h0 * h0;
            const float th0 = A * w0b;
            const float d0  = g0[i] * A;
            const float td0 = fmaf(tg0[i], A, -2.0f * g0[i] * h0 * th0);
            grad0 = fmaf(w0a, d0,  grad0);
            hvp0  = fmaf(w0a, td0, hvp0);
            hvp1  = fmaf(w0b, td0, hvp1);
        }
    }

    const float a = (grad0 - hvp0 * x1) / (hvp1 + EPSL);

    // Reference output dtype is float32: out[s][0] = v (= x1), out[s][1] = a.
    float2 o;
    o.x = x1;
    o.y = a;
    *(float2*)(out + 2 * s) = o;
}

extern "C" void kernel_launch(void* const* d_in, const int* in_sizes, int n_in,
                              void* d_out, int out_size, void* d_ws, size_t ws_size,
                              hipStream_t stream) {
    // setup_inputs order: t, x, W0, b0, W1, b1, W2, b2, W3, b3
    const float* x  = (const float*)d_in[1];
    const float* W0 = (const float*)d_in[2];
    const float* b0 = (const float*)d_in[3];
    const float* W1 = (const float*)d_in[4];
    const float* b1 = (const float*)d_in[5];
    const float* W2 = (const float*)d_in[6];
    const float* b2 = (const float*)d_in[7];
    const float* W3 = (const float*)d_in[8];
    // b3 (d_in[9]) does not affect gradients/Hessian — unused.

    float* W1T = (float*)d_ws;

    const int B = in_sizes[1] / 2;   // 1048576

    transpose64<<<HH, HH, 0, stream>>>(W1, W1T);
    lnn_kernel<<<B / BLK, BLK, 0, stream>>>(x, W0, b0, W1, b1, W2, b2, W3, W1T,
                                            (float*)d_out);
}

// Round 3
// 944.835 us; speedup vs baseline: 1.7327x; 1.7327x over previous
//
#include <hip/hip_runtime.h>
#include <hip/hip_bf16.h>
#include <hip/hip_fp16.h>

#define HH  64
#define BLK 64
#define EPSL 0.1f

// tanh via hardware exp + hardware rcp (1-ulp class). Saturates correctly:
// x->+inf: e=inf, rcp=0 -> 1; x->-inf: e=0 -> 1-2 = -1.
__device__ __forceinline__ float fast_tanh(float x) {
    float e = __expf(2.0f * x);
    return 1.0f - 2.0f * __builtin_amdgcn_rcpf(e + 1.0f);
}

// Tiny pre-pass: W1T[j][i] = W1[i][j] so phase F can s_load contiguous columns.
__global__ void transpose64(const float* __restrict__ W, float* __restrict__ WT) {
    int i = threadIdx.x;   // 0..63
    int j = blockIdx.x;    // 0..63
    WT[j * HH + i] = W[i * HH + j];
}

extern "C" __global__ void __launch_bounds__(BLK)
lnn_kernel(const float* __restrict__ x,
           const float* __restrict__ W0, const float* __restrict__ b0,
           const float* __restrict__ W1, const float* __restrict__ b1,
           const float* __restrict__ W2, const float* __restrict__ b2,
           const float* __restrict__ W3,
           const float* __restrict__ W1T,
           float* __restrict__ out)
{
    // Per-thread staging of (h1,th1) pairs — packed half2 so LDS/block is
    // 16 KB -> 10 blocks/CU residency (fp32 pairs gave 32 KB -> 5 blocks/CU).
    // Reused as (dz1, t_dz1) between phases E and F.
    __shared__ __half2 hs[HH][BLK];

    const int tid = threadIdx.x;
    const long s = (long)blockIdx.x * BLK + tid;

    const float2 xv = *(const float2*)(x + 2 * s);
    const float x0 = xv.x, x1 = xv.y;

    // ---------------- Phase B: z1/tz1 accumulation (h0 computed on the fly)
    {
        float z1[HH], tz1[HH];
        #pragma unroll
        for (int j = 0; j < HH; ++j) { z1[j] = b1[j]; tz1[j] = 0.0f; }

        #pragma unroll 1
        for (int i = 0; i < HH; ++i) {
            const float w0a = W0[i];          // W0[0][i]
            const float w0b = W0[HH + i];     // W0[1][i]
            const float z0  = fmaf(x0, w0a, fmaf(x1, w0b, b0[i]));
            const float h0  = fast_tanh(z0);
            const float th0 = (1.0f - h0 * h0) * w0b;   // tangent dir e1
            const float* __restrict__ row = W1 + i * HH;
            #pragma unroll
            for (int j = 0; j < HH; ++j) {
                const float w = row[j];
                z1[j]  = fmaf(h0,  w, z1[j]);
                tz1[j] = fmaf(th0, w, tz1[j]);
            }
        }
        // epilogue: (h1, th1) -> LDS as half2
        #pragma unroll
        for (int j = 0; j < HH; ++j) {
            const float h1  = fast_tanh(z1[j]);
            const float th1 = (1.0f - h1 * h1) * tz1[j];
            hs[j][tid] = __floats2half2_rn(h1, th1);
        }
    }

    // ---------------- Phase C: z2/tz2 accumulation, then transform to dz2/t_dz2
    float dz2[HH], tdz2[HH];   // first hold z2/tz2, transformed in place
    {
        #pragma unroll
        for (int j = 0; j < HH; ++j) { dz2[j] = b2[j]; tdz2[j] = 0.0f; }

        #pragma unroll 1
        for (int i = 0; i < HH; ++i) {
            const float2 ht = __half22float2(hs[i][tid]);
            const float h1  = ht.x;
            const float th1 = ht.y;
            const float* __restrict__ row = W2 + i * HH;
            #pragma unroll
            for (int j = 0; j < HH; ++j) {
                const float w = row[j];
                dz2[j]  = fmaf(h1,  w, dz2[j]);
                tdz2[j] = fmaf(th1, w, tdz2[j]);
            }
        }
        // D epilogue: dz2 = W3*(1-h2^2), t_dz2 = -2*W3*h2*th2
        #pragma unroll
        for (int j = 0; j < HH; ++j) {
            const float h2  = fast_tanh(dz2[j]);
            const float A   = 1.0f - h2 * h2;
            const float th2 = A * tdz2[j];
            const float w3  = W3[j];
            dz2[j]  = w3 * A;
            tdz2[j] = -2.0f * w3 * h2 * th2;
        }
    }

    // ---------------- Phase E: g1/tg1 per i, transform to dz1/t_dz1 (reuse LDS slots)
    #pragma unroll 1
    for (int i = 0; i < HH; ++i) {
        const float* __restrict__ row = W2 + i * HH;
        float g1 = 0.0f, tg1 = 0.0f;
        #pragma unroll
        for (int j = 0; j < HH; ++j) {
            const float w = row[j];
            g1  = fmaf(w, dz2[j],  g1);
            tg1 = fmaf(w, tdz2[j], tg1);
        }
        const float2 ht = __half22float2(hs[i][tid]);
        const float h1  = ht.x;
        const float th1 = ht.y;
        const float A   = 1.0f - h1 * h1;
        const float d1  = g1 * A;
        const float td1 = fmaf(tg1, A, -2.0f * g1 * h1 * th1);
        hs[i][tid] = __floats2half2_rn(d1, td1);   // (dz1, t_dz1)
    }

    // ---------------- Phase F: g0/tg0 accumulation over j (needs W1 columns = W1T rows)
    float grad0 = 0.0f, hvp0 = 0.0f, hvp1 = 0.0f;
    {
        float g0[HH], tg0[HH];
        #pragma unroll
        for (int i = 0; i < HH; ++i) { g0[i] = 0.0f; tg0[i] = 0.0f; }

        #pragma unroll 1
        for (int j = 0; j < HH; ++j) {
            const float2 dt = __half22float2(hs[j][tid]);
            const float d1  = dt.x;
            const float td1 = dt.y;
            const float* __restrict__ row = W1T + j * HH;
            #pragma unroll
            for (int i = 0; i < HH; ++i) {
                const float w = row[i];
                g0[i]  = fmaf(w, d1,  g0[i]);
                tg0[i] = fmaf(w, td1, tg0[i]);
            }
        }
        // epilogue: recompute h0, fold into the three scalar dots
        #pragma unroll
        for (int i = 0; i < HH; ++i) {
            const float w0a = W0[i];
            const float w0b = W0[HH + i];
            const float z0  = fmaf(x0, w0a, fmaf(x1, w0b, b0[i]));
            const float h0  = fast_tanh(z0);
            const float A   = 1.0f - h0 * h0;
            const float th0 = A * w0b;
            const float d0  = g0[i] * A;
            const float td0 = fmaf(tg0[i], A, -2.0f * g0[i] * h0 * th0);
            grad0 = fmaf(w0a, d0,  grad0);
            hvp0  = fmaf(w0a, td0, hvp0);
            hvp1  = fmaf(w0b, td0, hvp1);
        }
    }

    const float a = (grad0 - hvp0 * x1) / (hvp1 + EPSL);

    // Reference output dtype is float32: out[s] = {v (= x1), a}.
    float2 o;
    o.x = x1;
    o.y = a;
    *(float2*)(out + 2 * s) = o;
}

extern "C" void kernel_launch(void* const* d_in, const int* in_sizes, int n_in,
                              void* d_out, int out_size, void* d_ws, size_t ws_size,
                              hipStream_t stream) {
    // setup_inputs order: t, x, W0, b0, W1, b1, W2, b2, W3, b3
    const float* x  = (const float*)d_in[1];
    const float* W0 = (const float*)d_in[2];
    const float* b0 = (const float*)d_in[3];
    const float* W1 = (const float*)d_in[4];
    const float* b1 = (const float*)d_in[5];
    const float* W2 = (const float*)d_in[6];
    const float* b2 = (const float*)d_in[7];
    const float* W3 = (const float*)d_in[8];
    // b3 (d_in[9]) does not affect gradients/Hessian — unused.

    float* W1T = (float*)d_ws;

    const int B = in_sizes[1] / 2;   // 1048576

    transpose64<<<HH, HH, 0, stream>>>(W1, W1T);
    lnn_kernel<<<B / BLK, BLK, 0, stream>>>(x, W0, b0, W1, b1, W2, b2, W3, W1T,
                                            (float*)d_out);
}

// Round 4
// 413.379 us; speedup vs baseline: 3.9602x; 2.2856x over previous
//
#include <hip/hip_runtime.h>
#include <hip/hip_fp16.h>

typedef _Float16 half8 __attribute__((ext_vector_type(8)));
typedef float    f32x4 __attribute__((ext_vector_type(4)));

#define EPSL 0.1f
#define LDSW 68   // half2 cells per row: 68*4B = 272B rows, 16B-aligned

__device__ __forceinline__ float fast_tanh(float x) {
    float e = __expf(2.0f * x);
    return 1.0f - 2.0f * __builtin_amdgcn_rcpf(e + 1.0f);
}

// Pre-pack W1/W2 (fp32 -> fp16) into MFMA fragment layouts in d_ws.
// mat 0: W1 as B-frag  B[k=f0][n=f1] = W1[k*64+n]   (GEMM1: z1 = h0 @ W1)
// mat 1: W2 as B-frag  B[k=f1][n=f2] = W2[k*64+n]   (GEMM2: z2 = h1 @ W2)
// mat 2: W2T as B-frag B[k=f2][n=f1] = W2[n*64+k]   (GEMM3: g1 = dz2 @ W2T)
// mat 3: W1 as A-frag  A[m=f0][k=f1] = W1[m*64+k]   (GEMM4: g0T = W1 @ dz1T)
// Fragment layout (16x16x32): A[m=lane&15][k=(lane>>4)*8+j]; B[k=(lane>>4)*8+j][n=lane&15].
// Stored so each lane's 8 elements are contiguous: pk[((mat*2+kt)*4+nt)*512 + lane*8 + j].
__global__ void pack_weights(const float* __restrict__ W1,
                             const float* __restrict__ W2,
                             _Float16* __restrict__ pk) {
    const int t = threadIdx.x;        // 0..63
    const int q = t >> 4, r = t & 15;
    for (int kt = 0; kt < 2; ++kt)
        for (int nt = 0; nt < 4; ++nt)
            for (int j = 0; j < 8; ++j) {
                const int k = kt * 32 + q * 8 + j;
                const int n = nt * 16 + r;   // plays role of m for mat 3
                const int base = ((kt * 4 + nt) * 64 + t) * 8 + j;
                pk[0 * 4096 + base] = (_Float16)W1[k * 64 + n];
                pk[1 * 4096 + base] = (_Float16)W2[k * 64 + n];
                pk[2 * 4096 + base] = (_Float16)W2[n * 64 + k];
                pk[3 * 4096 + base] = (_Float16)W1[n * 64 + k];
            }
}

extern "C" __global__ void __launch_bounds__(64, 2)
lnn_mfma(const float* __restrict__ x,
         const float* __restrict__ W0, const float* __restrict__ b0,
         const float* __restrict__ b1, const float* __restrict__ b2,
         const float* __restrict__ W3,
         const _Float16* __restrict__ pk,
         float* __restrict__ out)
{
    __shared__ unsigned int lds[64 * LDSW];   // half2 cells: (value, tangent)

    const int t = threadIdx.x;
    const int q = t >> 4;
    const int r = t & 15;
    const long base = (long)blockIdx.x * 64;

    const float2 xv = *(const float2*)(x + 2 * (base + t));

    // B-frag / A-frag weight load: one 16B load per (mat,kt,tile)
    auto ldpk = [&](int mat, int kt, int nt) -> half8 {
        return *(const half8*)(pk + ((mat * 2 + kt) * 4 + nt) * 512 + t * 8);
    };
    // LDS C->frag read: 8 contiguous half2 at (row, k=kt*32+q*8..+7), split into
    // value-frag (low halves) and tangent-frag (high halves) via v_perm.
    auto ldfrag = [&](int row, int kt, half8& vf, half8& tf) {
        const int off = row * LDSW + kt * 32 + q * 8;
        const uint4 A = *(const uint4*)&lds[off];
        const uint4 B = *(const uint4*)&lds[off + 4];
        union { unsigned int u[4]; half8 h; } cv, ct;
        cv.u[0] = __builtin_amdgcn_perm(A.y, A.x, 0x05040100u);
        cv.u[1] = __builtin_amdgcn_perm(A.w, A.z, 0x05040100u);
        cv.u[2] = __builtin_amdgcn_perm(B.y, B.x, 0x05040100u);
        cv.u[3] = __builtin_amdgcn_perm(B.w, B.z, 0x05040100u);
        ct.u[0] = __builtin_amdgcn_perm(A.y, A.x, 0x07060302u);
        ct.u[1] = __builtin_amdgcn_perm(A.w, A.z, 0x07060302u);
        ct.u[2] = __builtin_amdgcn_perm(B.y, B.x, 0x07060302u);
        ct.u[3] = __builtin_amdgcn_perm(B.w, B.z, 0x07060302u);
        vf = cv.h; tf = ct.h;
    };

    // ---------------- P0: h0 / th0 directly in A-frag layout
    float x0m[4], x1m[4];
    #pragma unroll
    for (int mt = 0; mt < 4; ++mt) {
        x0m[mt] = __shfl(xv.x, mt * 16 + r);
        x1m[mt] = __shfl(xv.y, mt * 16 + r);
    }
    half8 ah0[4][2], at0[4][2];
    #pragma unroll
    for (int kt = 0; kt < 2; ++kt) {
        const int f = kt * 32 + q * 8;
        const float4 waA = *(const float4*)(W0 + f);
        const float4 waB = *(const float4*)(W0 + f + 4);
        const float4 wbA = *(const float4*)(W0 + 64 + f);
        const float4 wbB = *(const float4*)(W0 + 64 + f + 4);
        const float4 bbA = *(const float4*)(b0 + f);
        const float4 bbB = *(const float4*)(b0 + f + 4);
        const float wa[8] = {waA.x, waA.y, waA.z, waA.w, waB.x, waB.y, waB.z, waB.w};
        const float wb[8] = {wbA.x, wbA.y, wbA.z, wbA.w, wbB.x, wbB.y, wbB.z, wbB.w};
        const float bb[8] = {bbA.x, bbA.y, bbA.z, bbA.w, bbB.x, bbB.y, bbB.z, bbB.w};
        #pragma unroll
        for (int mt = 0; mt < 4; ++mt) {
            #pragma unroll
            for (int j = 0; j < 8; ++j) {
                const float z0 = fmaf(x0m[mt], wa[j], fmaf(x1m[mt], wb[j], bb[j]));
                const float h0 = fast_tanh(z0);
                const float A0 = fmaf(-h0, h0, 1.0f);
                ah0[mt][kt][j] = (_Float16)h0;
                at0[mt][kt][j] = (_Float16)(A0 * wb[j]);
            }
        }
    }

    // ---------------- GEMM1: z1 = h0 @ W1 ; tz1 = th0 @ W1
    f32x4 acc[4][4], tacc[4][4];
    #pragma unroll
    for (int mt = 0; mt < 4; ++mt)
        #pragma unroll
        for (int nt = 0; nt < 4; ++nt) {
            acc[mt][nt] = (f32x4){0.f, 0.f, 0.f, 0.f};
            tacc[mt][nt] = (f32x4){0.f, 0.f, 0.f, 0.f};
        }
    #pragma unroll
    for (int kt = 0; kt < 2; ++kt)
        #pragma unroll
        for (int nt = 0; nt < 4; ++nt) {
            const half8 bw = ldpk(0, kt, nt);
            #pragma unroll
            for (int mt = 0; mt < 4; ++mt) {
                acc[mt][nt]  = __builtin_amdgcn_mfma_f32_16x16x32_f16(ah0[mt][kt], bw, acc[mt][nt], 0, 0, 0);
                tacc[mt][nt] = __builtin_amdgcn_mfma_f32_16x16x32_f16(at0[mt][kt], bw, tacc[mt][nt], 0, 0, 0);
            }
        }

    // ---------------- P1: h1/th1 (C-layout). Keep packed in regs + write LDS.
    unsigned int h1p[4][4][4];
    {
        float b1f[4];
        #pragma unroll
        for (int nt = 0; nt < 4; ++nt) b1f[nt] = b1[nt * 16 + r];
        #pragma unroll
        for (int mt = 0; mt < 4; ++mt)
            #pragma unroll
            for (int nt = 0; nt < 4; ++nt)
                #pragma unroll
                for (int g = 0; g < 4; ++g) {
                    const float z1 = acc[mt][nt][g] + b1f[nt];
                    const float h1 = fast_tanh(z1);
                    const float th1 = fmaf(-h1, h1, 1.0f) * tacc[mt][nt][g];
                    const __half2 hh = __floats2half2_rn(h1, th1);
                    const unsigned int u = *(const unsigned int*)&hh;
                    h1p[mt][nt][g] = u;
                    lds[(mt * 16 + q * 4 + g) * LDSW + nt * 16 + r] = u;
                }
    }
    __syncthreads();

    // ---------------- GEMM2: z2 = h1 @ W2 ; tz2 = th1 @ W2
    #pragma unroll
    for (int mt = 0; mt < 4; ++mt)
        #pragma unroll
        for (int nt = 0; nt < 4; ++nt) {
            acc[mt][nt] = (f32x4){0.f, 0.f, 0.f, 0.f};
            tacc[mt][nt] = (f32x4){0.f, 0.f, 0.f, 0.f};
        }
    #pragma unroll
    for (int kt = 0; kt < 2; ++kt) {
        half8 av[4], at[4];
        #pragma unroll
        for (int mt = 0; mt < 4; ++mt) ldfrag(mt * 16 + r, kt, av[mt], at[mt]);
        #pragma unroll
        for (int nt = 0; nt < 4; ++nt) {
            const half8 bw = ldpk(1, kt, nt);
            #pragma unroll
            for (int mt = 0; mt < 4; ++mt) {
                acc[mt][nt]  = __builtin_amdgcn_mfma_f32_16x16x32_f16(av[mt], bw, acc[mt][nt], 0, 0, 0);
                tacc[mt][nt] = __builtin_amdgcn_mfma_f32_16x16x32_f16(at[mt], bw, tacc[mt][nt], 0, 0, 0);
            }
        }
    }
    __syncthreads();

    // ---------------- P2: dz2 = W3*(1-h2^2) ; tdz2 = -2*W3*h2*th2 -> LDS
    {
        float b2f[4], w3f[4];
        #pragma unroll
        for (int nt = 0; nt < 4; ++nt) { b2f[nt] = b2[nt * 16 + r]; w3f[nt] = W3[nt * 16 + r]; }
        #pragma unroll
        for (int mt = 0; mt < 4; ++mt)
            #pragma unroll
            for (int nt = 0; nt < 4; ++nt)
                #pragma unroll
                for (int g = 0; g < 4; ++g) {
                    const float z2 = acc[mt][nt][g] + b2f[nt];
                    const float h2 = fast_tanh(z2);
                    const float A2 = fmaf(-h2, h2, 1.0f);
                    const float th2 = A2 * tacc[mt][nt][g];
                    const float dz2 = w3f[nt] * A2;
                    const float td2 = -2.0f * w3f[nt] * h2 * th2;
                    const __half2 hh = __floats2half2_rn(dz2, td2);
                    lds[(mt * 16 + q * 4 + g) * LDSW + nt * 16 + r] = *(const unsigned int*)&hh;
                }
    }
    __syncthreads();

    // ---------------- GEMM3: g1 = dz2 @ W2T ; tg1 = tdz2 @ W2T
    #pragma unroll
    for (int mt = 0; mt < 4; ++mt)
        #pragma unroll
        for (int nt = 0; nt < 4; ++nt) {
            acc[mt][nt] = (f32x4){0.f, 0.f, 0.f, 0.f};
            tacc[mt][nt] = (f32x4){0.f, 0.f, 0.f, 0.f};
        }
    #pragma unroll
    for (int kt = 0; kt < 2; ++kt) {
        half8 av[4], at[4];
        #pragma unroll
        for (int mt = 0; mt < 4; ++mt) ldfrag(mt * 16 + r, kt, av[mt], at[mt]);
        #pragma unroll
        for (int nt = 0; nt < 4; ++nt) {
            const half8 bw = ldpk(2, kt, nt);
            #pragma unroll
            for (int mt = 0; mt < 4; ++mt) {
                acc[mt][nt]  = __builtin_amdgcn_mfma_f32_16x16x32_f16(av[mt], bw, acc[mt][nt], 0, 0, 0);
                tacc[mt][nt] = __builtin_amdgcn_mfma_f32_16x16x32_f16(at[mt], bw, tacc[mt][nt], 0, 0, 0);
            }
        }
    }
    __syncthreads();

    // ---------------- P3: dz1 = g1*A1 ; tdz1 = tg1*A1 - 2*g1*h1*th1 -> LDS
    #pragma unroll
    for (int mt = 0; mt < 4; ++mt)
        #pragma unroll
        for (int nt = 0; nt < 4; ++nt)
            #pragma unroll
            for (int g = 0; g < 4; ++g) {
                const float g1 = acc[mt][nt][g];
                const float tg1 = tacc[mt][nt][g];
                const float2 ht = __half22float2(*(const __half2*)&h1p[mt][nt][g]);
                const float A1 = fmaf(-ht.x, ht.x, 1.0f);
                const float d1 = g1 * A1;
                const float u = g1 * ht.x * ht.y;
                const float td1 = fmaf(tg1, A1, -2.0f * u);
                const __half2 hh = __floats2half2_rn(d1, td1);
                lds[(mt * 16 + q * 4 + g) * LDSW + nt * 16 + r] = *(const unsigned int*)&hh;
            }
    __syncthreads();

    // ---------------- GEMM4 (transposed): g0T = W1 @ dz1T ; tg0T = W1 @ tdz1T
    // C'[m=f0][n=sample]: feature dim lands in-lane -> cheap final reduction.
    #pragma unroll
    for (int mt = 0; mt < 4; ++mt)
        #pragma unroll
        for (int nt = 0; nt < 4; ++nt) {
            acc[mt][nt] = (f32x4){0.f, 0.f, 0.f, 0.f};
            tacc[mt][nt] = (f32x4){0.f, 0.f, 0.f, 0.f};
        }
    #pragma unroll
    for (int kt = 0; kt < 2; ++kt) {
        half8 bd[4], btd[4];
        #pragma unroll
        for (int nt = 0; nt < 4; ++nt) ldfrag(nt * 16 + r, kt, bd[nt], btd[nt]);
        #pragma unroll
        for (int mt = 0; mt < 4; ++mt) {
            const half8 aw = ldpk(3, kt, mt);
            #pragma unroll
            for (int nt = 0; nt < 4; ++nt) {
                acc[mt][nt]  = __builtin_amdgcn_mfma_f32_16x16x32_f16(aw, bd[nt],  acc[mt][nt], 0, 0, 0);
                tacc[mt][nt] = __builtin_amdgcn_mfma_f32_16x16x32_f16(aw, btd[nt], tacc[mt][nt], 0, 0, 0);
            }
        }
    }

    // ---------------- P4: recompute h0 at (f0, sample), fold into 3 dots,
    // reduce over features: in-lane (mt,g) + cross-quad shfl_xor(16,32).
    float x0n[4], x1n[4];
    #pragma unroll
    for (int nt = 0; nt < 4; ++nt) {
        x0n[nt] = __shfl(xv.x, nt * 16 + r);
        x1n[nt] = __shfl(xv.y, nt * 16 + r);
    }
    float pg[4] = {0.f, 0.f, 0.f, 0.f};
    float ph0[4] = {0.f, 0.f, 0.f, 0.f};
    float ph1[4] = {0.f, 0.f, 0.f, 0.f};
    #pragma unroll
    for (int mt = 0; mt < 4; ++mt) {
        const int f = mt * 16 + q * 4;
        const float4 waF = *(const float4*)(W0 + f);
        const float4 wbF = *(const float4*)(W0 + 64 + f);
        const float4 b0F = *(const float4*)(b0 + f);
        const float wa[4] = {waF.x, waF.y, waF.z, waF.w};
        const float wb[4] = {wbF.x, wbF.y, wbF.z, wbF.w};
        const float bb[4] = {b0F.x, b0F.y, b0F.z, b0F.w};
        #pragma unroll
        for (int g = 0; g < 4; ++g) {
            #pragma unroll
            for (int nt = 0; nt < 4; ++nt) {
                const float z0 = fmaf(x0n[nt], wa[g], fmaf(x1n[nt], wb[g], bb[g]));
                const float h0 = fast_tanh(z0);
                const float A0 = fmaf(-h0, h0, 1.0f);
                const float th0 = A0 * wb[g];
                const float g0 = acc[mt][nt][g];
                const float tg0 = tacc[mt][nt][g];
                const float d0 = g0 * A0;
                const float u = g0 * h0 * th0;
                const float td0 = fmaf(-2.0f, u, tg0 * A0);
                pg[nt]  = fmaf(wa[g], d0, pg[nt]);
                ph0[nt] = fmaf(wa[g], td0, ph0[nt]);
                ph1[nt] = fmaf(wb[g], td0, ph1[nt]);
            }
        }
    }
    #pragma unroll
    for (int nt = 0; nt < 4; ++nt) {
        pg[nt]  += __shfl_xor(pg[nt], 16);  pg[nt]  += __shfl_xor(pg[nt], 32);
        ph0[nt] += __shfl_xor(ph0[nt], 16); ph0[nt] += __shfl_xor(ph0[nt], 32);
        ph1[nt] += __shfl_xor(ph1[nt], 16); ph1[nt] += __shfl_xor(ph1[nt], 32);
        if (q == nt) {
            const float num = fmaf(-ph0[nt], x1n[nt], pg[nt]);
            const float a = num / (ph1[nt] + EPSL);
            float2 o;
            o.x = x1n[nt];
            o.y = a;
            *(float2*)(out + 2 * (base + nt * 16 + r)) = o;
        }
    }
}

extern "C" void kernel_launch(void* const* d_in, const int* in_sizes, int n_in,
                              void* d_out, int out_size, void* d_ws, size_t ws_size,
                              hipStream_t stream) {
    // setup_inputs order: t, x, W0, b0, W1, b1, W2, b2, W3, b3
    const float* x  = (const float*)d_in[1];
    const float* W0 = (const float*)d_in[2];
    const float* b0 = (const float*)d_in[3];
    const float* W1 = (const float*)d_in[4];
    const float* b1 = (const float*)d_in[5];
    const float* W2 = (const float*)d_in[6];
    const float* b2 = (const float*)d_in[7];
    const float* W3 = (const float*)d_in[8];
    // b3 unused (no effect on grad/Hessian)

    _Float16* pk = (_Float16*)d_ws;   // 4 mats * 4096 halfs = 32 KB
    const int B = in_sizes[1] / 2;    // 1048576

    pack_weights<<<1, 64, 0, stream>>>(W1, W2, pk);
    lnn_mfma<<<B / 64, 64, 0, stream>>>(x, W0, b0, b1, b2, W3, pk, (float*)d_out);
}

// Round 5
// 255.198 us; speedup vs baseline: 6.4150x; 1.6198x over previous
//
#include <hip/hip_runtime.h>
#include <hip/hip_fp16.h>

typedef _Float16 half8 __attribute__((ext_vector_type(8)));
typedef float    f32x4 __attribute__((ext_vector_type(4)));

#define EPSL 0.1f
#define LDSW 68   // half2 cells per row: 272B rows, 16B-aligned, 2-way-bank-free

__device__ __forceinline__ float fast_tanh(float x) {
    float e = __expf(2.0f * x);
    return 1.0f - 2.0f * __builtin_amdgcn_rcpf(e + 1.0f);
}

// Pre-pack W1/W2 (fp32 -> fp16) into MFMA fragment layouts in d_ws.
// mat 0: W1 as B-frag  B[k=f0][n=f1] = W1[k*64+n]   (GEMM1: z1 = h0 @ W1)
// mat 1: W2 as B-frag  B[k=f1][n=f2] = W2[k*64+n]   (GEMM2: z2 = h1 @ W2)
// mat 2: W2T as B-frag B[k=f2][n=f1] = W2[n*64+k]   (GEMM3: g1 = dz2 @ W2T)
// mat 3: W1 as A-frag  A[m=f0][k=f1] = W1[m*64+k]   (GEMM4: g0T = W1 @ dz1T)
// A[m=lane&15][k=(lane>>4)*8+j]; B[k=(lane>>4)*8+j][n=lane&15];
// stored lane-contiguous: pk[((mat*2+kt)*4+nt)*512 + lane*8 + j].
__global__ void pack_weights(const float* __restrict__ W1,
                             const float* __restrict__ W2,
                             _Float16* __restrict__ pk) {
    const int t = threadIdx.x;        // 0..63
    const int q = t >> 4, r = t & 15;
    for (int kt = 0; kt < 2; ++kt)
        for (int nt = 0; nt < 4; ++nt)
            for (int j = 0; j < 8; ++j) {
                const int k = kt * 32 + q * 8 + j;
                const int n = nt * 16 + r;   // plays role of m for mat 3
                const int base = ((kt * 4 + nt) * 64 + t) * 8 + j;
                pk[0 * 4096 + base] = (_Float16)W1[k * 64 + n];
                pk[1 * 4096 + base] = (_Float16)W2[k * 64 + n];
                pk[2 * 4096 + base] = (_Float16)W2[n * 64 + k];
                pk[3 * 4096 + base] = (_Float16)W1[n * 64 + k];
            }
}

extern "C" __global__ void __launch_bounds__(256, 3)
lnn_mfma(const float* __restrict__ x,
         const float* __restrict__ W0, const float* __restrict__ b0,
         const float* __restrict__ b1, const float* __restrict__ b2,
         const float* __restrict__ W3,
         const _Float16* __restrict__ pk,
         float* __restrict__ out)
{
    // 4 independent waves per block; wave w owns LDS rows [w*16, w*16+16).
    // No __syncthreads anywhere — all staging is intra-wave.
    __shared__ unsigned int lds[64 * LDSW];

    const int t    = threadIdx.x & 63;
    const int w    = threadIdx.x >> 6;
    const int q    = t >> 4;
    const int r    = t & 15;
    const int wrow = w * 16;
    const long sbase = (long)blockIdx.x * 64 + wrow;  // this wave's 16 samples

    // lane holds sample (sbase + r); quads are the k/row partition
    const float2 xv = *(const float2*)(x + 2 * (sbase + r));
    const float x0 = xv.x, x1 = xv.y;

    auto ldpk = [&](int mat, int kt, int nt) -> half8 {
        return *(const half8*)(pk + ((mat * 2 + kt) * 4 + nt) * 512 + t * 8);
    };
    // LDS C->frag: 8 half2 at (row, k=kt*32+q*8..+7) -> value frag + tangent frag
    auto ldfrag = [&](int row, int kt, half8& vf, half8& tf) {
        const int off = row * LDSW + kt * 32 + q * 8;
        const uint4 A = *(const uint4*)&lds[off];
        const uint4 B = *(const uint4*)&lds[off + 4];
        union { unsigned int u[4]; half8 h; } cv, ct;
        cv.u[0] = __builtin_amdgcn_perm(A.y, A.x, 0x05040100u);
        cv.u[1] = __builtin_amdgcn_perm(A.w, A.z, 0x05040100u);
        cv.u[2] = __builtin_amdgcn_perm(B.y, B.x, 0x05040100u);
        cv.u[3] = __builtin_amdgcn_perm(B.w, B.z, 0x05040100u);
        ct.u[0] = __builtin_amdgcn_perm(A.y, A.x, 0x07060302u);
        ct.u[1] = __builtin_amdgcn_perm(A.w, A.z, 0x07060302u);
        ct.u[2] = __builtin_amdgcn_perm(B.y, B.x, 0x07060302u);
        ct.u[3] = __builtin_amdgcn_perm(B.w, B.z, 0x07060302u);
        vf = cv.h; tf = ct.h;
    };

    // ---------------- P0: h0/th0 directly in A-frag layout (m=sample r, k=f0)
    half8 ah0[2], at0[2];
    #pragma unroll
    for (int kt = 0; kt < 2; ++kt) {
        const int f = kt * 32 + q * 8;
        const float4 waA = *(const float4*)(W0 + f);
        const float4 waB = *(const float4*)(W0 + f + 4);
        const float4 wbA = *(const float4*)(W0 + 64 + f);
        const float4 wbB = *(const float4*)(W0 + 64 + f + 4);
        const float4 bbA = *(const float4*)(b0 + f);
        const float4 bbB = *(const float4*)(b0 + f + 4);
        const float wa[8] = {waA.x, waA.y, waA.z, waA.w, waB.x, waB.y, waB.z, waB.w};
        const float wb[8] = {wbA.x, wbA.y, wbA.z, wbA.w, wbB.x, wbB.y, wbB.z, wbB.w};
        const float bb[8] = {bbA.x, bbA.y, bbA.z, bbA.w, bbB.x, bbB.y, bbB.z, bbB.w};
        #pragma unroll
        for (int j = 0; j < 8; ++j) {
            const float z0 = fmaf(x0, wa[j], fmaf(x1, wb[j], bb[j]));
            const float h0 = fast_tanh(z0);
            const float A0 = fmaf(-h0, h0, 1.0f);
            ah0[kt][j] = (_Float16)h0;
            at0[kt][j] = (_Float16)(A0 * wb[j]);
        }
    }

    // ---------------- GEMM1: z1 = h0 @ W1 ; tz1 = th0 @ W1
    f32x4 acc[4], tacc[4];
    #pragma unroll
    for (int nt = 0; nt < 4; ++nt) { acc[nt] = (f32x4){0,0,0,0}; tacc[nt] = (f32x4){0,0,0,0}; }
    #pragma unroll
    for (int kt = 0; kt < 2; ++kt)
        #pragma unroll
        for (int nt = 0; nt < 4; ++nt) {
            const half8 bw = ldpk(0, kt, nt);
            acc[nt]  = __builtin_amdgcn_mfma_f32_16x16x32_f16(ah0[kt], bw, acc[nt], 0, 0, 0);
            tacc[nt] = __builtin_amdgcn_mfma_f32_16x16x32_f16(at0[kt], bw, tacc[nt], 0, 0, 0);
        }

    // ---------------- P1: h1/th1 at (sample=q*4+g, f1=nt*16+r); keep + LDS
    unsigned int h1p[4][4];
    #pragma unroll
    for (int nt = 0; nt < 4; ++nt) {
        const float b1f = b1[nt * 16 + r];
        #pragma unroll
        for (int g = 0; g < 4; ++g) {
            const float z1 = acc[nt][g] + b1f;
            const float h1 = fast_tanh(z1);
            const float th1 = fmaf(-h1, h1, 1.0f) * tacc[nt][g];
            const __half2 hh = __floats2half2_rn(h1, th1);
            const unsigned int u = *(const unsigned int*)&hh;
            h1p[nt][g] = u;
            lds[(wrow + q * 4 + g) * LDSW + nt * 16 + r] = u;
        }
    }
    __builtin_amdgcn_wave_barrier();

    // ---------------- GEMM2: z2 = h1 @ W2 ; tz2 = th1 @ W2
    #pragma unroll
    for (int nt = 0; nt < 4; ++nt) { acc[nt] = (f32x4){0,0,0,0}; tacc[nt] = (f32x4){0,0,0,0}; }
    #pragma unroll
    for (int kt = 0; kt < 2; ++kt) {
        half8 av, at;
        ldfrag(wrow + r, kt, av, at);
        #pragma unroll
        for (int nt = 0; nt < 4; ++nt) {
            const half8 bw = ldpk(1, kt, nt);
            acc[nt]  = __builtin_amdgcn_mfma_f32_16x16x32_f16(av, bw, acc[nt], 0, 0, 0);
            tacc[nt] = __builtin_amdgcn_mfma_f32_16x16x32_f16(at, bw, tacc[nt], 0, 0, 0);
        }
    }
    __builtin_amdgcn_wave_barrier();

    // ---------------- P2: dz2 = W3*(1-h2^2) ; tdz2 = -2*W3*h2*th2 -> LDS
    #pragma unroll
    for (int nt = 0; nt < 4; ++nt) {
        const float b2f = b2[nt * 16 + r];
        const float w3f = W3[nt * 16 + r];
        #pragma unroll
        for (int g = 0; g < 4; ++g) {
            const float z2 = acc[nt][g] + b2f;
            const float h2 = fast_tanh(z2);
            const float A2 = fmaf(-h2, h2, 1.0f);
            const float th2 = A2 * tacc[nt][g];
            const float dz2 = w3f * A2;
            const float td2 = -2.0f * w3f * h2 * th2;
            const __half2 hh = __floats2half2_rn(dz2, td2);
            lds[(wrow + q * 4 + g) * LDSW + nt * 16 + r] = *(const unsigned int*)&hh;
        }
    }
    __builtin_amdgcn_wave_barrier();

    // ---------------- GEMM3: g1 = dz2 @ W2T ; tg1 = tdz2 @ W2T
    #pragma unroll
    for (int nt = 0; nt < 4; ++nt) { acc[nt] = (f32x4){0,0,0,0}; tacc[nt] = (f32x4){0,0,0,0}; }
    #pragma unroll
    for (int kt = 0; kt < 2; ++kt) {
        half8 av, at;
        ldfrag(wrow + r, kt, av, at);
        #pragma unroll
        for (int nt = 0; nt < 4; ++nt) {
            const half8 bw = ldpk(2, kt, nt);
            acc[nt]  = __builtin_amdgcn_mfma_f32_16x16x32_f16(av, bw, acc[nt], 0, 0, 0);
            tacc[nt] = __builtin_amdgcn_mfma_f32_16x16x32_f16(at, bw, tacc[nt], 0, 0, 0);
        }
    }
    __builtin_amdgcn_wave_barrier();

    // ---------------- P3: dz1 = g1*A1 ; tdz1 = tg1*A1 - 2*g1*h1*th1 -> LDS
    #pragma unroll
    for (int nt = 0; nt < 4; ++nt)
        #pragma unroll
        for (int g = 0; g < 4; ++g) {
            const float g1 = acc[nt][g];
            const float tg1 = tacc[nt][g];
            const float2 ht = __half22float2(*(const __half2*)&h1p[nt][g]);
            const float A1 = fmaf(-ht.x, ht.x, 1.0f);
            const float d1 = g1 * A1;
            const float u = g1 * ht.x * ht.y;
            const float td1 = fmaf(tg1, A1, -2.0f * u);
            const __half2 hh = __floats2half2_rn(d1, td1);
            lds[(wrow + q * 4 + g) * LDSW + nt * 16 + r] = *(const unsigned int*)&hh;
        }
    __builtin_amdgcn_wave_barrier();

    // ---------------- GEMM4 (transposed): g0T = W1 @ dz1T ; tg0T = W1 @ tdz1T
    // C'[m=f0][n=sample]: feature dim in-lane -> cheap final reduction.
    #pragma unroll
    for (int mt = 0; mt < 4; ++mt) { acc[mt] = (f32x4){0,0,0,0}; tacc[mt] = (f32x4){0,0,0,0}; }
    #pragma unroll
    for (int kt = 0; kt < 2; ++kt) {
        half8 bd, btd;
        ldfrag(wrow + r, kt, bd, btd);
        #pragma unroll
        for (int mt = 0; mt < 4; ++mt) {
            const half8 aw = ldpk(3, kt, mt);
            acc[mt]  = __builtin_amdgcn_mfma_f32_16x16x32_f16(aw, bd,  acc[mt], 0, 0, 0);
            tacc[mt] = __builtin_amdgcn_mfma_f32_16x16x32_f16(aw, btd, tacc[mt], 0, 0, 0);
        }
    }

    // ---------------- P4: recompute h0 at (f0 = mt*16+q*4+g, own sample r),
    // fold into 3 dots; reduce over features: 16 in-lane + shfl_xor(16,32).
    float pg = 0.f, ph0 = 0.f, ph1 = 0.f;
    #pragma unroll
    for (int mt = 0; mt < 4; ++mt) {
        const int f = mt * 16 + q * 4;
        const float4 waF = *(const float4*)(W0 + f);
        const float4 wbF = *(const float4*)(W0 + 64 + f);
        const float4 b0F = *(const float4*)(b0 + f);
        const float wa[4] = {waF.x, waF.y, waF.z, waF.w};
        const float wb[4] = {wbF.x, wbF.y, wbF.z, wbF.w};
        const float bb[4] = {b0F.x, b0F.y, b0F.z, b0F.w};
        #pragma unroll
        for (int g = 0; g < 4; ++g) {
            const float z0 = fmaf(x0, wa[g], fmaf(x1, wb[g], bb[g]));
            const float h0 = fast_tanh(z0);
            const float A0 = fmaf(-h0, h0, 1.0f);
            const float th0 = A0 * wb[g];
            const float g0 = acc[mt][g];
            const float tg0 = tacc[mt][g];
            const float d0 = g0 * A0;
            const float u = g0 * h0 * th0;
            const float td0 = fmaf(-2.0f, u, tg0 * A0);
            pg  = fmaf(wa[g], d0, pg);
            ph0 = fmaf(wa[g], td0, ph0);
            ph1 = fmaf(wb[g], td0, ph1);
        }
    }
    pg  += __shfl_xor(pg, 16);  pg  += __shfl_xor(pg, 32);
    ph0 += __shfl_xor(ph0, 16); ph0 += __shfl_xor(ph0, 32);
    ph1 += __shfl_xor(ph1, 16); ph1 += __shfl_xor(ph1, 32);
    if (q == 0) {
        const float num = fmaf(-ph0, x1, pg);
        const float a = num / (ph1 + EPSL);
        float2 o;
        o.x = x1;
        o.y = a;
        *(float2*)(out + 2 * (sbase + r)) = o;
    }
}

extern "C" void kernel_launch(void* const* d_in, const int* in_sizes, int n_in,
                              void* d_out, int out_size, void* d_ws, size_t ws_size,
                              hipStream_t stream) {
    // setup_inputs order: t, x, W0, b0, W1, b1, W2, b2, W3, b3
    const float* x  = (const float*)d_in[1];
    const float* W0 = (const float*)d_in[2];
    const float* b0 = (const float*)d_in[3];
    const float* W1 = (const float*)d_in[4];
    const float* b1 = (const float*)d_in[5];
    const float* W2 = (const float*)d_in[6];
    const float* b2 = (const float*)d_in[7];
    const float* W3 = (const float*)d_in[8];
    // b3 unused (no effect on grad/Hessian)

    _Float16* pk = (_Float16*)d_ws;   // 4 mats * 4096 halfs = 32 KB
    const int B = in_sizes[1] / 2;    // 1048576

    pack_weights<<<1, 64, 0, stream>>>(W1, W2, pk);
    // 256-thread blocks = 4 independent waves x 16 samples each
    lnn_mfma<<<B / 64, 256, 0, stream>>>(x, W0, b0, b1, b2, W3, pk, (float*)d_out);
}

// Round 7
// 224.357 us; speedup vs baseline: 7.2968x; 1.1375x over previous
//
#include <hip/hip_runtime.h>
#include <hip/hip_fp16.h>

typedef _Float16 half8 __attribute__((ext_vector_type(8)));
typedef float    f32x4 __attribute__((ext_vector_type(4)));

#define EPSL 0.1f
#define LDSW 68   // uint cells per row: 272B rows, 16B-aligned, ~2-way banks (free)

__device__ __forceinline__ float fast_tanh(float x) {
    float e = __expf(2.0f * x);
    return 1.0f - 2.0f * __builtin_amdgcn_rcpf(e + 1.0f);
}

// v_cvt_pkrtz_f16_f32: pack two f32 into one uint (lo=a, hi=b), 1 inst.
// NB: the builtin returns __fp16-vector, not _Float16-vector.
__device__ __forceinline__ unsigned int pk2(float a, float b) {
    union { __fp16 __attribute__((ext_vector_type(2))) h; unsigned int u; } v;
    v.h = __builtin_amdgcn_cvt_pkrtz(a, b);
    return v.u;
}
__device__ __forceinline__ float2 unpk2(unsigned int u) {
    union { unsigned int u; __half2 h; } v; v.u = u;
    return __half22float2(v.h);
}

// Pre-pack W1/W2 (fp32 -> fp16) into MFMA fragment layouts in d_ws.
// mat 0: W1 as B-frag  (GEMM1: z1 = h0 @ W1)
// mat 1: W2 as B-frag  (GEMM2: z2 = h1 @ W2)
// mat 2: W2T as B-frag (GEMM3: g1 = dz2 @ W2T)
// mat 3: W1 as A-frag  (GEMM4: g0T = W1 @ dz1T)
// A[m=lane&15][k=(lane>>4)*8+j]; B[k=(lane>>4)*8+j][n=lane&15];
// stored lane-contiguous: pk[((mat*2+kt)*4+nt)*512 + lane*8 + j].
__global__ void pack_weights(const float* __restrict__ W1,
                             const float* __restrict__ W2,
                             _Float16* __restrict__ pk) {
    const int t = threadIdx.x;        // 0..63
    const int q = t >> 4, r = t & 15;
    for (int kt = 0; kt < 2; ++kt)
        for (int nt = 0; nt < 4; ++nt)
            for (int j = 0; j < 8; ++j) {
                const int k = kt * 32 + q * 8 + j;
                const int n = nt * 16 + r;   // plays role of m for mat 3
                const int base = ((kt * 4 + nt) * 64 + t) * 8 + j;
                pk[0 * 4096 + base] = (_Float16)W1[k * 64 + n];
                pk[1 * 4096 + base] = (_Float16)W2[k * 64 + n];
                pk[2 * 4096 + base] = (_Float16)W2[n * 64 + k];
                pk[3 * 4096 + base] = (_Float16)W1[n * 64 + k];
            }
}

extern "C" __global__ void __launch_bounds__(256, 3)
lnn_mfma(const float* __restrict__ x,
         const float* __restrict__ W0, const float* __restrict__ b0,
         const float* __restrict__ b1, const float* __restrict__ b2,
         const float* __restrict__ W3,
         const _Float16* __restrict__ pk,
         float* __restrict__ out)
{
    // 4 independent waves per block; wave w owns rows [w*16, w*16+16).
    __shared__ unsigned int lds [64 * LDSW];  // (value, tangent) half2 staging
    __shared__ unsigned int lds2[64 * LDSW];  // (h0, th0) pairs: row=sample, col=feature

    const int t    = threadIdx.x & 63;
    const int w    = threadIdx.x >> 6;
    const int q    = t >> 4;
    const int r    = t & 15;
    const int wrow = w * 16;
    const long sbase = (long)blockIdx.x * 64 + wrow;  // this wave's 16 samples

    const float2 xv = *(const float2*)(x + 2 * (sbase + r));
    const float x0 = xv.x, x1 = xv.y;

    auto ldpk = [&](int mat, int kt, int nt) -> half8 {
        return *(const half8*)(pk + ((mat * 2 + kt) * 4 + nt) * 512 + t * 8);
    };
    // LDS C->frag: 8 half2 at (row, k=kt*32+q*8..+7) -> value frag + tangent frag
    auto ldfrag = [&](int row, int kt, half8& vf, half8& tf) {
        const int off = row * LDSW + kt * 32 + q * 8;
        const uint4 A = *(const uint4*)&lds[off];
        const uint4 B = *(const uint4*)&lds[off + 4];
        union { unsigned int u[4]; half8 h; } cv, ct;
        cv.u[0] = __builtin_amdgcn_perm(A.y, A.x, 0x05040100u);
        cv.u[1] = __builtin_amdgcn_perm(A.w, A.z, 0x05040100u);
        cv.u[2] = __builtin_amdgcn_perm(B.y, B.x, 0x05040100u);
        cv.u[3] = __builtin_amdgcn_perm(B.w, B.z, 0x05040100u);
        ct.u[0] = __builtin_amdgcn_perm(A.y, A.x, 0x07060302u);
        ct.u[1] = __builtin_amdgcn_perm(A.w, A.z, 0x07060302u);
        ct.u[2] = __builtin_amdgcn_perm(B.y, B.x, 0x07060302u);
        ct.u[3] = __builtin_amdgcn_perm(B.w, B.z, 0x07060302u);
        vf = cv.h; tf = ct.h;
    };

    // ---------------- P0: h0/th0 in A-frag layout + stage pairs to lds2
    half8 ah0[2], at0[2];
    #pragma unroll
    for (int kt = 0; kt < 2; ++kt) {
        const int f = kt * 32 + q * 8;
        const float4 waA = *(const float4*)(W0 + f);
        const float4 waB = *(const float4*)(W0 + f + 4);
        const float4 wbA = *(const float4*)(W0 + 64 + f);
        const float4 wbB = *(const float4*)(W0 + 64 + f + 4);
        const float4 bbA = *(const float4*)(b0 + f);
        const float4 bbB = *(const float4*)(b0 + f + 4);
        const float wa[8] = {waA.x, waA.y, waA.z, waA.w, waB.x, waB.y, waB.z, waB.w};
        const float wb[8] = {wbA.x, wbA.y, wbA.z, wbA.w, wbB.x, wbB.y, wbB.z, wbB.w};
        const float bb[8] = {bbA.x, bbA.y, bbA.z, bbA.w, bbB.x, bbB.y, bbB.z, bbB.w};
        float h0v[8], t0v[8];
        #pragma unroll
        for (int j = 0; j < 8; ++j) {
            const float z0 = fmaf(x0, wa[j], fmaf(x1, wb[j], bb[j]));
            const float h0 = fast_tanh(z0);
            h0v[j] = h0;
            t0v[j] = fmaf(-h0, h0, 1.0f) * wb[j];
        }
        union { unsigned int u[4]; half8 h; } ph, pt;
        uint4 s0, s1;
        #pragma unroll
        for (int p = 0; p < 4; ++p) {
            ph.u[p] = pk2(h0v[2 * p], h0v[2 * p + 1]);
            pt.u[p] = pk2(t0v[2 * p], t0v[2 * p + 1]);
        }
        s0.x = pk2(h0v[0], t0v[0]); s0.y = pk2(h0v[1], t0v[1]);
        s0.z = pk2(h0v[2], t0v[2]); s0.w = pk2(h0v[3], t0v[3]);
        s1.x = pk2(h0v[4], t0v[4]); s1.y = pk2(h0v[5], t0v[5]);
        s1.z = pk2(h0v[6], t0v[6]); s1.w = pk2(h0v[7], t0v[7]);
        *(uint4*)&lds2[(wrow + r) * LDSW + f]     = s0;
        *(uint4*)&lds2[(wrow + r) * LDSW + f + 4] = s1;
        ah0[kt] = ph.h; at0[kt] = pt.h;
    }

    // ---------------- GEMM1: z1 = h0 @ W1 ; tz1 = th0 @ W1
    f32x4 acc[4], tacc[4];
    #pragma unroll
    for (int nt = 0; nt < 4; ++nt) { acc[nt] = (f32x4){0,0,0,0}; tacc[nt] = (f32x4){0,0,0,0}; }
    #pragma unroll
    for (int kt = 0; kt < 2; ++kt)
        #pragma unroll
        for (int nt = 0; nt < 4; ++nt) {
            const half8 bw = ldpk(0, kt, nt);
            acc[nt]  = __builtin_amdgcn_mfma_f32_16x16x32_f16(ah0[kt], bw, acc[nt], 0, 0, 0);
            tacc[nt] = __builtin_amdgcn_mfma_f32_16x16x32_f16(at0[kt], bw, tacc[nt], 0, 0, 0);
        }

    // ---------------- P1: h1/th1 at (sample=q*4+g, f1=nt*16+r); keep + LDS
    unsigned int h1p[4][4];
    #pragma unroll
    for (int nt = 0; nt < 4; ++nt) {
        const float b1f = b1[nt * 16 + r];
        #pragma unroll
        for (int g = 0; g < 4; ++g) {
            const float z1 = acc[nt][g] + b1f;
            const float h1 = fast_tanh(z1);
            const float th1 = fmaf(-h1, h1, 1.0f) * tacc[nt][g];
            const unsigned int u = pk2(h1, th1);
            h1p[nt][g] = u;
            lds[(wrow + q * 4 + g) * LDSW + nt * 16 + r] = u;
        }
    }
    __builtin_amdgcn_wave_barrier();

    // ---------------- GEMM2: z2 = h1 @ W2 ; tz2 = th1 @ W2
    #pragma unroll
    for (int nt = 0; nt < 4; ++nt) { acc[nt] = (f32x4){0,0,0,0}; tacc[nt] = (f32x4){0,0,0,0}; }
    #pragma unroll
    for (int kt = 0; kt < 2; ++kt) {
        half8 av, at;
        ldfrag(wrow + r, kt, av, at);
        #pragma unroll
        for (int nt = 0; nt < 4; ++nt) {
            const half8 bw = ldpk(1, kt, nt);
            acc[nt]  = __builtin_amdgcn_mfma_f32_16x16x32_f16(av, bw, acc[nt], 0, 0, 0);
            tacc[nt] = __builtin_amdgcn_mfma_f32_16x16x32_f16(at, bw, tacc[nt], 0, 0, 0);
        }
    }
    __builtin_amdgcn_wave_barrier();

    // ---------------- P2: dz2 = W3*A2 ; tdz2 = -2*h2*dz2*tz2 -> LDS
    #pragma unroll
    for (int nt = 0; nt < 4; ++nt) {
        const float b2f = b2[nt * 16 + r];
        const float w3f = W3[nt * 16 + r];
        #pragma unroll
        for (int g = 0; g < 4; ++g) {
            const float z2 = acc[nt][g] + b2f;
            const float h2 = fast_tanh(z2);
            const float A2 = fmaf(-h2, h2, 1.0f);
            const float dz2 = w3f * A2;
            const float t1  = h2 * tacc[nt][g];
            const float td2 = -2.0f * (dz2 * t1);
            lds[(wrow + q * 4 + g) * LDSW + nt * 16 + r] = pk2(dz2, td2);
        }
    }
    __builtin_amdgcn_wave_barrier();

    // ---------------- GEMM3: g1 = dz2 @ W2T ; tg1 = tdz2 @ W2T
    #pragma unroll
    for (int nt = 0; nt < 4; ++nt) { acc[nt] = (f32x4){0,0,0,0}; tacc[nt] = (f32x4){0,0,0,0}; }
    #pragma unroll
    for (int kt = 0; kt < 2; ++kt) {
        half8 av, at;
        ldfrag(wrow + r, kt, av, at);
        #pragma unroll
        for (int nt = 0; nt < 4; ++nt) {
            const half8 bw = ldpk(2, kt, nt);
            acc[nt]  = __builtin_amdgcn_mfma_f32_16x16x32_f16(av, bw, acc[nt], 0, 0, 0);
            tacc[nt] = __builtin_amdgcn_mfma_f32_16x16x32_f16(at, bw, tacc[nt], 0, 0, 0);
        }
    }
    __builtin_amdgcn_wave_barrier();

    // ---------------- P3: dz1 = g1*A1 ; tdz1 = tg1*A1 - 2*g1*h1*th1 -> LDS
    #pragma unroll
    for (int nt = 0; nt < 4; ++nt)
        #pragma unroll
        for (int g = 0; g < 4; ++g) {
            const float g1 = acc[nt][g];
            const float tg1 = tacc[nt][g];
            const float2 ht = unpk2(h1p[nt][g]);
            const float A1 = fmaf(-ht.x, ht.x, 1.0f);
            const float d1 = g1 * A1;
            const float u = g1 * ht.x * ht.y;
            const float td1 = fmaf(tg1, A1, -2.0f * u);
            lds[(wrow + q * 4 + g) * LDSW + nt * 16 + r] = pk2(d1, td1);
        }
    __builtin_amdgcn_wave_barrier();

    // ---------------- GEMM4 (transposed): g0T = W1 @ dz1T ; tg0T = W1 @ tdz1T
    #pragma unroll
    for (int mt = 0; mt < 4; ++mt) { acc[mt] = (f32x4){0,0,0,0}; tacc[mt] = (f32x4){0,0,0,0}; }
    #pragma unroll
    for (int kt = 0; kt < 2; ++kt) {
        half8 bd, btd;
        ldfrag(wrow + r, kt, bd, btd);
        #pragma unroll
        for (int mt = 0; mt < 4; ++mt) {
            const half8 aw = ldpk(3, kt, mt);
            acc[mt]  = __builtin_amdgcn_mfma_f32_16x16x32_f16(aw, bd,  acc[mt], 0, 0, 0);
            tacc[mt] = __builtin_amdgcn_mfma_f32_16x16x32_f16(aw, btd, tacc[mt], 0, 0, 0);
        }
    }

    // ---------------- P4: read staged (h0,th0), fold into 3 dots,
    // reduce over features: 16 in-lane + shfl_xor(16,32).
    float pg = 0.f, ph0 = 0.f, ph1 = 0.f;
    #pragma unroll
    for (int mt = 0; mt < 4; ++mt) {
        const int f = mt * 16 + q * 4;
        const float4 waF = *(const float4*)(W0 + f);
        const float4 wbF = *(const float4*)(W0 + 64 + f);
        const float wa[4] = {waF.x, waF.y, waF.z, waF.w};
        const float wb[4] = {wbF.x, wbF.y, wbF.z, wbF.w};
        const uint4 hh = *(const uint4*)&lds2[(wrow + r) * LDSW + f];
        const unsigned int hu[4] = {hh.x, hh.y, hh.z, hh.w};
        #pragma unroll
        for (int g = 0; g < 4; ++g) {
            const float2 ht = unpk2(hu[g]);
            const float h0 = ht.x, th0 = ht.y;
            const float A0 = fmaf(-h0, h0, 1.0f);
            const float g0 = acc[mt][g];
            const float tg0 = tacc[mt][g];
            const float d0 = g0 * A0;
            const float u = g0 * h0 * th0;
            const float td0 = fmaf(-2.0f, u, tg0 * A0);
            pg  = fmaf(wa[g], d0, pg);
            ph0 = fmaf(wa[g], td0, ph0);
            ph1 = fmaf(wb[g], td0, ph1);
        }
    }
    pg  += __shfl_xor(pg, 16);  pg  += __shfl_xor(pg, 32);
    ph0 += __shfl_xor(ph0, 16); ph0 += __shfl_xor(ph0, 32);
    ph1 += __shfl_xor(ph1, 16); ph1 += __shfl_xor(ph1, 32);
    if (q == 0) {
        const float num = fmaf(-ph0, x1, pg);
        const float a = num / (ph1 + EPSL);
        float2 o;
        o.x = x1;
        o.y = a;
        *(float2*)(out + 2 * (sbase + r)) = o;
    }
}

extern "C" void kernel_launch(void* const* d_in, const int* in_sizes, int n_in,
                              void* d_out, int out_size, void* d_ws, size_t ws_size,
                              hipStream_t stream) {
    // setup_inputs order: t, x, W0, b0, W1, b1, W2, b2, W3, b3
    const float* x  = (const float*)d_in[1];
    const float* W0 = (const float*)d_in[2];
    const float* b0 = (const float*)d_in[3];
    const float* W1 = (const float*)d_in[4];
    const float* b1 = (const float*)d_in[5];
    const float* W2 = (const float*)d_in[6];
    const float* b2 = (const float*)d_in[7];
    const float* W3 = (const float*)d_in[8];
    // b3 unused (no effect on grad/Hessian)

    _Float16* pk = (_Float16*)d_ws;   // 4 mats * 4096 halfs = 32 KB
    const int B = in_sizes[1] / 2;    // 1048576

    pack_weights<<<1, 64, 0, stream>>>(W1, W2, pk);
    // 256-thread blocks = 4 independent waves x 16 samples each
    lnn_mfma<<<B / 64, 256, 0, stream>>>(x, W0, b0, b1, b2, W3, pk, (float*)d_out);
}